// Round 9
// baseline (249.221 us; speedup 1.0000x reference)
//
#include <hip/hip_runtime.h>
#include <stdint.h>

#define DIM   2048
#define LSEQ  2048
#define BATCH 2
#define NH    32
#define NKV   8
#define HD    64
#define M_ROWS (BATCH*LSEQ)       // 4096
#define NQKV  (DIM + 2*NKV*HD)    // 3072
#define KOFF  DIM                 // 2048
#define VOFF  (DIM + NKV*HD)      // 2560

typedef __attribute__((ext_vector_type(8))) __bf16 bf16x8;
typedef __attribute__((ext_vector_type(8))) unsigned short u16x8;
typedef __attribute__((ext_vector_type(4))) float f32x4;

// hardware RNE f32->bf16 (harness-verified rounds 2-8)
__device__ __forceinline__ unsigned short f2bf(float f) {
  union { __bf16 h; unsigned short u; } v;
  v.h = (__bf16)f;
  return v.u;
}
__device__ __forceinline__ float bf2f(unsigned short h) {
  union { unsigned u; float f; } v; v.u = ((unsigned)h) << 16;
  return v.f;
}

__device__ __forceinline__ void gload_lds16(const void* g, void* l) {
  __builtin_amdgcn_global_load_lds(
      (__attribute__((address_space(1))) unsigned int*)g,
      (__attribute__((address_space(3))) unsigned int*)l, 16, 0, 0);
}

// ---------------- fp32 -> bf16 convert (vectorized) ----------------
__global__ void k_cvt_x(const float* __restrict__ in, unsigned short* __restrict__ out, int n4) {
  int i = blockIdx.x * blockDim.x + threadIdx.x;
  if (i >= n4) return;
  float4 v = ((const float4*)in)[i];
  ushort4 o;
  o.x = f2bf(v.x); o.y = f2bf(v.y); o.z = f2bf(v.z); o.w = f2bf(v.w);
  ((ushort4*)out)[i] = o;
}

// ---------------- transpose + cast + scale: out[n][k] = bf16(scale*in[k][n]) ----------------
// scale folds softmax 1/sqrt(d)*log2(e) into wq (commutes with RoPE rotation + GEMM).
__global__ void k_transpose_bf16(const float* __restrict__ in, unsigned short* __restrict__ out,
                                 int K, int N, float scale) {
  __shared__ float tile[32][33];
  int n0 = blockIdx.x * 32, k0 = blockIdx.y * 32;
  int tx = threadIdx.x, ty = threadIdx.y;
  #pragma unroll
  for (int i = ty; i < 32; i += 8)
    tile[i][tx] = in[(long)(k0 + i) * N + n0 + tx];
  __syncthreads();
  #pragma unroll
  for (int i = ty; i < 32; i += 8)
    out[(long)(n0 + i) * K + k0 + tx] = f2bf(scale * tile[tx][i]);
}

// ---------------- transpose V section of qkv -> vT, k-PERMUTED columns ----------------
// Column position e holds original k = tx with e = 8*((tx>>2)&3) + 4*(tx>>4) + (tx&3),
// matching flash's in-register-P A-fragment k-order (round 6/7, verified).
__global__ void k_transpose_v(const unsigned short* __restrict__ qkv,
                              unsigned short* __restrict__ vT) {
  __shared__ unsigned short tile[32][33];
  int c0 = blockIdx.x * 32;   // within 512 (= g*64+d)
  int l0 = blockIdx.y * 32;
  int b  = blockIdx.z;
  int tx = threadIdx.x, ty = threadIdx.y;
  #pragma unroll
  for (int i = ty; i < 32; i += 8)
    tile[i][tx] = qkv[((long)b * LSEQ + l0 + i) * NQKV + VOFF + c0 + tx];
  __syncthreads();
  int e = 8 * ((tx >> 2) & 3) + 4 * (tx >> 4) + (tx & 3);
  #pragma unroll
  for (int i = ty; i < 32; i += 8)
    vT[((long)b * 512 + c0 + i) * LSEQ + l0 + e] = tile[tx][i];
}

// ---------------- RoPE tables ----------------
__global__ void k_rope_table(float* __restrict__ cosT, float* __restrict__ sinT) {
  int i = blockIdx.x * 256 + threadIdx.x;  // < LSEQ*32
  int t = i >> 5, j = i & 31;
  float inv = powf(10000.0f, -(float)j / 32.0f);
  float fr = (float)t * inv;
  cosT[i] = cosf(fr);
  sinT[i] = sinf(fr);
}

// ---------------- GEMM v4: 64x128 tile, m97 K-loop, grid-occupancy fix ----------------
// Round-9: round-8 showed the GEMM is GRID-limited (QKV 768 blocks = 3/CU exactly;
// VGPR 72 / LDS 16KB limit nothing; Occ 28%, MfmaUtil 26%). 64(M)x128(N) tile doubles
// the grid: QKV 1536 = 6 blocks/CU, WO 1024 = 4/CU -> 6 waves/SIMD hide the per-K-step
// vmcnt drain. N-span 128 keeps each wave's 64-col quadrant head-aligned, so the
// verified in-register RoPE epilogue carries over. LDS 12KB/block.
// Bank-conflict fix (was 6.3M cy, 8-way): slot-swizzle byte ^= ((row&3)<<4), both-sides
// (rule #21): inverse-swizzled global source col (t&3)^((t>>2)&3), swizzled ds_read with
// lane-constant (fr&3)<<4 (row&3 == fr&3 since wr, i*16 are multiples of 4). 8->4-way.
// Wave map: 2M x 2N quadrants of 32x64; af[2], bfv[4], acc[2][4], 8 MFMA/wave/K-step.
template<bool BF16OUT, bool ROPE>
__global__ __launch_bounds__(256) void k_gemm_bt(
    const unsigned short* __restrict__ A, const unsigned short* __restrict__ Bt,
    void* __restrict__ Cv, int M, int N, int K,
    const float* __restrict__ cosT, const float* __restrict__ sinT) {
  __shared__ unsigned short As[64 * 32];    // 4KB: A-tile [64 m][32 k], slot-swizzled
  __shared__ unsigned short Bs[128 * 32];   // 8KB: B-tile [128 n][32 k], slot-swizzled
  int t = threadIdx.x;
  int lane = t & 63, wave = t >> 6;
  int fr = lane & 15, fg = lane >> 4;
  long rowA = (long)blockIdx.x * 64;
  long rowB = (long)blockIdx.y * 128;
  // staging: thread t -> LDS row t>>2 (linear dest), slot t&3; source element-block
  // inverse-swizzled: e = (t&3) ^ ((t>>2)&3)  (involution; read side XORs the same).
  int esw = ((t & 3) ^ ((t >> 2) & 3)) * 8;
  const unsigned short* Ap  = A  + (rowA + (t >> 2)) * (long)K + esw;
  const unsigned short* Bp  = Bt + (rowB + (t >> 2)) * (long)K + esw;
  const unsigned short* Bp2 = Bp + 64 * (long)K;
  f32x4 acc[2][4] = {};
  int wr = (wave >> 1) * 32, wc = (wave & 1) * 64;
  int sw4 = (fr & 3) << 4;                  // read-side XOR: row&3 == fr&3
  char* AsB = (char*)As; char* BsB = (char*)Bs;
  for (int kt = 0; kt < K; kt += 32) {
    gload_lds16(Ap + kt,  AsB + t * 16);
    gload_lds16(Bp + kt,  BsB + t * 16);
    gload_lds16(Bp2 + kt, BsB + 4096 + t * 16);
    __syncthreads();
    bf16x8 af[2], bfv[4];
    #pragma unroll
    for (int i = 0; i < 2; i++)
      af[i] = *(const bf16x8*)(AsB + (wr + i * 16 + fr) * 64 + ((fg * 16) ^ sw4));
    #pragma unroll
    for (int j = 0; j < 4; j++)
      bfv[j] = *(const bf16x8*)(BsB + (wc + j * 16 + fr) * 64 + ((fg * 16) ^ sw4));
    #pragma unroll
    for (int i = 0; i < 2; i++) {
      #pragma unroll
      for (int j = 0; j < 4; j++)
        acc[i][j] = __builtin_amdgcn_mfma_f32_16x16x32_bf16(af[i], bfv[j], acc[i][j], 0, 0, 0);
    }
    __syncthreads();
  }

  long colbase = rowB + wc;
  bool rope_sec = ROPE && (colbase < VOFF);   // Q or K head (col < 2560); wave-uniform
  #pragma unroll
  for (int i = 0; i < 2; i++) {
    #pragma unroll
    for (int r = 0; r < 4; r++) {
      long row = rowA + wr + i * 16 + fg * 4 + r;
      if (ROPE && rope_sec) {
        int tpos = (int)(row & (LSEQ - 1));
        #pragma unroll
        for (int j = 0; j < 2; j++) {   // pair (d = j*16+fr, d+32 = (j+2)*16+fr)
          int jj = j * 16 + fr;
          float c = cosT[tpos * 32 + jj];
          float s = sinT[tpos * 32 + jj];
          float lo = acc[i][j][r], hi = acc[i][j + 2][r];
          ((unsigned short*)Cv)[row * N + colbase + j * 16 + fr]       = f2bf(lo * c - hi * s);
          ((unsigned short*)Cv)[row * N + colbase + (j + 2) * 16 + fr] = f2bf(hi * c + lo * s);
        }
      } else {
        #pragma unroll
        for (int j = 0; j < 4; j++) {
          long col = colbase + j * 16 + fr;
          if (BF16OUT) ((unsigned short*)Cv)[row * N + col] = f2bf(acc[i][j][r]);
          else         ((float*)Cv)[row * N + col] = acc[i][j][r];
        }
      }
    }
  }
}

// ---------------- flash attention v16: in-register P (round-7, verified) ----------------
// Swapped QK (mfma(K,Q)) -> P lane-local per q-column; register-only bf16 pack
// (static-index vector inserts -- the round-6 union idiom went to scratch, rule #20);
// V k-order permuted in k_transpose_v to match A-frag slot order; static-max softmax
// (wq pre-scaled into exp2 domain); LDS 48KB -> 3 blocks/CU.
__global__ __launch_bounds__(256, 3) void k_flash_attn13(
    const unsigned short* __restrict__ qkv, const unsigned short* __restrict__ vT,
    unsigned short* __restrict__ attn) {
  int g0 = (int)blockIdx.x;
  int hb = g0 & 63;
  int h = hb & 31, b = hb >> 5;
  int qt = 15 - (g0 >> 6);            // heavy blocks first (backfill smooths the tail)
  int g = h >> 2;
  int t = threadIdx.x, lane = t & 63, wave = t >> 6;
  int fr = lane & 15, fg = lane >> 4;

  __shared__ __align__(16) char KT[16384];              // 16KB: K tile [128 rows][128B], swz
  __shared__ __align__(16) char VT2[2][16384];          // 32KB: V tile [64 rows][256B], swz, dbuf
  long rowbase = (long)b * LSEQ;

  int qbaseA = qt * 128 + wave * 32;
  int qbaseB = qbaseA + 16;

  const unsigned short* qpA = &qkv[(rowbase + qbaseA + fr) * NQKV + h * 64 + fg * 8];
  const unsigned short* qpB = &qkv[(rowbase + qbaseB + fr) * NQKV + h * 64 + fg * 8];
  bf16x8 qfA0 = *(const bf16x8*)(qpA);
  bf16x8 qfA1 = *(const bf16x8*)(qpA + 32);
  bf16x8 qfB0 = *(const bf16x8*)(qpB);
  bf16x8 qfB1 = *(const bf16x8*)(qpB + 32);

  int kcb = ((t & 7) * 16) ^ (((t >> 3) & 7) << 4);    // K: 128B rows, row = p*32 + (t>>3)
  int vcb = ((t & 15) * 16) ^ (((t >> 4) & 7) << 4);   // V: 256B rows, row = p*16 + (t>>4)

  const char* kgb = (const char*)qkv;
  const char* vgb = (const char*)vT;
  long ksrc0 = ((rowbase) * (long)NQKV + KOFF + (long)g * 64) * 2;
  long vsrc0 = (((long)(b * 512 + g * 64)) * LSEQ) * 2;

  auto stageK = [&](int kbase) {
    #pragma unroll
    for (int p = 0; p < 4; p++) {
      int krow = p * 32 + (t >> 3);
      gload_lds16(kgb + ksrc0 + (long)(kbase + krow) * (NQKV * 2) + kcb,
                  KT + p * 4096 + t * 16);
    }
  };
  auto stageV = [&](int kbase, char* dst) {
    #pragma unroll
    for (int p = 0; p < 4; p++) {
      int vrow = p * 16 + (t >> 4);
      gload_lds16(vgb + vsrc0 + (long)vrow * (LSEQ * 2) + kbase * 2 + vcb,
                  dst + p * 4096 + t * 16);
    }
  };

  stageK(0);
  stageV(0, VT2[0]);

  f32x4 poA[4] = {}, poB[4] = {};
  float lA = 0.f, lB = 0.f;   // per-lane partial denominators for q = qbase+fr

  int sw8 = (fr & 7) << 4;

  for (int kt = 0; kt <= qt; kt++) {
    int kbase = kt * 128;
    __syncthreads();   // B1: staged K/V landed; all waves' prev-iter LDS reads done

    // V restage WAR-safe at B1 (prev PV readers of this buffer synced); full-iter cover
    if (kt < qt) stageV(kbase + 128, VT2[(kt + 1) & 1]);

    f32x4 stA[8], stB[8];
    __builtin_amdgcn_s_setprio(1);
    #pragma unroll
    for (int s = 0; s < 8; s++) {
      const char* kr = KT + ((s * 16 + fr) << 7);
      bf16x8 kf0 = *(const bf16x8*)(kr + ((fg * 16) ^ sw8));
      bf16x8 kf1 = *(const bf16x8*)(kr + ((fg * 16 + 64) ^ sw8));
      f32x4 a = {};
      a = __builtin_amdgcn_mfma_f32_16x16x32_bf16(kf0, qfA0, a, 0, 0, 0);
      a = __builtin_amdgcn_mfma_f32_16x16x32_bf16(kf1, qfA1, a, 0, 0, 0);
      stA[s] = a;
      f32x4 c = {};
      c = __builtin_amdgcn_mfma_f32_16x16x32_bf16(kf0, qfB0, c, 0, 0, 0);
      c = __builtin_amdgcn_mfma_f32_16x16x32_bf16(kf1, qfB1, c, 0, 0, 0);
      stB[s] = c;
    }
    __builtin_amdgcn_s_setprio(0);
    __syncthreads();   // B2: all waves' K ds_reads retired -> K restage safe

    if (kt < qt) stageK(kbase + 128);   // lands by next B1; softmax+PV cover

    if (kt == qt) {   // diagonal tile: causal mask (k = kbase+s*16+fg*4+r, q = qbase+fr)
      #pragma unroll
      for (int s = 0; s < 8; s++) {
        #pragma unroll
        for (int r = 0; r < 4; r++) {
          int kp = kbase + s * 16 + fg * 4 + r;
          if (kp > qbaseA + fr) stA[s][r] = -1e30f;
          if (kp > qbaseB + fr) stB[s][r] = -1e30f;
        }
      }
    }

    // softmax (static-max, pre-scaled exp2 domain) + register-only bf16 pack.
    // A-frag slot (fg, j): j=r -> k32 = 4*fg + r ; j=4+r -> k32 = 16 + 4*fg + r.
    bf16x8 paA[4], paB[4];
    #pragma unroll
    for (int km = 0; km < 4; km++) {
      bf16x8 pa, pb;
      #pragma unroll
      for (int r = 0; r < 4; r++) {
        float peA = exp2f(stA[2 * km][r]);
        float pqA = exp2f(stA[2 * km + 1][r]);
        lA += peA + pqA;
        pa[r]     = (__bf16)peA;
        pa[r + 4] = (__bf16)pqA;
        float peB = exp2f(stB[2 * km][r]);
        float pqB = exp2f(stB[2 * km + 1][r]);
        lB += peB + pqB;
        pb[r]     = (__bf16)peB;
        pb[r + 4] = (__bf16)pqB;
      }
      paA[km] = pa;
      paB[km] = pb;
    }

    const char* Vb = VT2[kt & 1];
    __builtin_amdgcn_s_setprio(1);
    #pragma unroll
    for (int km = 0; km < 4; km++) {
      #pragma unroll
      for (int dt = 0; dt < 4; dt++) {
        const char* vr = Vb + ((dt * 16 + fr) << 8);
        bf16x8 vf = *(const bf16x8*)(vr + ((km * 64 + fg * 16) ^ sw8));
        poA[dt] = __builtin_amdgcn_mfma_f32_16x16x32_bf16(paA[km], vf, poA[dt], 0, 0, 0);
        poB[dt] = __builtin_amdgcn_mfma_f32_16x16x32_bf16(paB[km], vf, poB[dt], 0, 0, 0);
      }
    }
    __builtin_amdgcn_s_setprio(0);
    // no trailing barrier: next B1 orders LDS reads vs. restaging
  }

  // denominator: reduce per-lane partials over the fg-group (lanes fr, fr+16, fr+32, fr+48)
  lA += __shfl_xor(lA, 16, 64); lA += __shfl_xor(lA, 32, 64);
  lB += __shfl_xor(lB, 16, 64); lB += __shfl_xor(lB, 32, 64);

  // po[dt][r] is O[q = qbase + fg*4 + r][d = dt*16 + fr]; l for q-local i lives on lanes
  // with fr == i -> fetch via shfl from lane fg*4+r (fg=0 copy).
  #pragma unroll
  for (int r = 0; r < 4; r++) {
    float liA = 1.0f / __shfl(lA, fg * 4 + r, 64);
    float liB = 1.0f / __shfl(lB, fg * 4 + r, 64);
    #pragma unroll
    for (int dt = 0; dt < 4; dt++) {
      attn[(rowbase + qbaseA + fg * 4 + r) * DIM + h * 64 + dt * 16 + fr] = f2bf(poA[dt][r] * liA);
      attn[(rowbase + qbaseB + fg * 4 + r) * DIM + h * 64 + dt * 16 + fr] = f2bf(poB[dt][r] * liB);
    }
  }
}

extern "C" void kernel_launch(void* const* d_in, const int* in_sizes, int n_in,
                              void* d_out, int out_size, void* d_ws, size_t ws_size,
                              hipStream_t stream) {
  const float* x  = (const float*)d_in[0];
  const float* wq = (const float*)d_in[1];
  const float* wk = (const float*)d_in[2];
  const float* wv = (const float*)d_in[3];
  const float* wo = (const float*)d_in[4];

  char* ws = (char*)d_ws;
  unsigned short* xb    = (unsigned short*)(ws);                 // 16.78 MB (reused as vT later)
  unsigned short* wqkvT = (unsigned short*)(ws + 16777216);      // 12.58 MB [3072][2048]
  unsigned short* woT   = (unsigned short*)(ws + 29360128);      //  8.39 MB [2048][2048]
  unsigned short* qkv   = (unsigned short*)(ws + 37748736);      // 25.17 MB [4096][3072]
  unsigned short* attn  = (unsigned short*)(ws + 62914560);      // 16.78 MB [4096][2048]
  float* cosT           = (float*)(ws + 79691776);               // 256 KB
  float* sinT           = (float*)(ws + 79953920);               // 256 KB
  unsigned short* vT    = xb;                                    // alias: xb dead after QKV GEMM

  const float C2 = 0.125f * 1.44269504f;   // 1/sqrt(64) * log2(e), folded into wq

  k_cvt_x<<<8192, 256, 0, stream>>>(x, xb, M_ROWS * DIM / 4);
  dim3 tb(32, 8);
  k_transpose_bf16<<<dim3(DIM/32, DIM/32), tb, 0, stream>>>(wq, wqkvT, DIM, DIM, C2);
  k_transpose_bf16<<<dim3(512/32, DIM/32), tb, 0, stream>>>(wk, wqkvT + (long)2048*2048, DIM, 512, 1.0f);
  k_transpose_bf16<<<dim3(512/32, DIM/32), tb, 0, stream>>>(wv, wqkvT + (long)2560*2048, DIM, 512, 1.0f);
  k_transpose_bf16<<<dim3(DIM/32, DIM/32), tb, 0, stream>>>(wo, woT, DIM, DIM, 1.0f);
  k_rope_table<<<(LSEQ*32)/256, 256, 0, stream>>>(cosT, sinT);

  // 64x128-tile GEMMs (grid-occupancy fix): QKV 64x24=1536 blocks (6/CU), WO 64x16=1024 (4/CU)
  k_gemm_bt<true, true><<<dim3(M_ROWS/64, NQKV/128), 256, 0, stream>>>(
      xb, wqkvT, qkv, M_ROWS, NQKV, DIM, cosT, sinT);
  k_transpose_v<<<dim3(16, 64, 2), tb, 0, stream>>>(qkv, vT);
  k_flash_attn13<<<1024, 256, 0, stream>>>(qkv, vT, attn);
  k_gemm_bt<false, false><<<dim3(M_ROWS/64, DIM/128), 256, 0, stream>>>(
      attn, woT, d_out, M_ROWS, DIM, DIM, nullptr, nullptr);
}

// Round 10
// 195.329 us; speedup vs baseline: 1.2759x; 1.2759x over previous
//
#include <hip/hip_runtime.h>
#include <stdint.h>

#define DIM   2048
#define LSEQ  2048
#define BATCH 2
#define NH    32
#define NKV   8
#define HD    64
#define M_ROWS (BATCH*LSEQ)       // 4096
#define NQKV  (DIM + 2*NKV*HD)    // 3072
#define KOFF  DIM                 // 2048
#define VOFF  (DIM + NKV*HD)      // 2560

typedef __attribute__((ext_vector_type(8))) __bf16 bf16x8;
typedef __attribute__((ext_vector_type(8))) unsigned short u16x8;
typedef __attribute__((ext_vector_type(4))) float f32x4;

// hardware RNE f32->bf16 (harness-verified rounds 2-9)
__device__ __forceinline__ unsigned short f2bf(float f) {
  union { __bf16 h; unsigned short u; } v;
  v.h = (__bf16)f;
  return v.u;
}
__device__ __forceinline__ float bf2f(unsigned short h) {
  union { unsigned u; float f; } v; v.u = ((unsigned)h) << 16;
  return v.f;
}

__device__ __forceinline__ void gload_lds16(const void* g, void* l) {
  __builtin_amdgcn_global_load_lds(
      (__attribute__((address_space(1))) unsigned int*)g,
      (__attribute__((address_space(3))) unsigned int*)l, 16, 0, 0);
}

// ---------------- fp32 -> bf16 convert (vectorized) ----------------
__global__ void k_cvt_x(const float* __restrict__ in, unsigned short* __restrict__ out, int n4) {
  int i = blockIdx.x * blockDim.x + threadIdx.x;
  if (i >= n4) return;
  float4 v = ((const float4*)in)[i];
  ushort4 o;
  o.x = f2bf(v.x); o.y = f2bf(v.y); o.z = f2bf(v.z); o.w = f2bf(v.w);
  ((ushort4*)out)[i] = o;
}

// ---------------- transpose + cast + scale: out[n][k] = bf16(scale*in[k][n]) ----------------
// scale folds softmax 1/sqrt(d)*log2(e) into wq (commutes with RoPE rotation + GEMM).
__global__ void k_transpose_bf16(const float* __restrict__ in, unsigned short* __restrict__ out,
                                 int K, int N, float scale) {
  __shared__ float tile[32][33];
  int n0 = blockIdx.x * 32, k0 = blockIdx.y * 32;
  int tx = threadIdx.x, ty = threadIdx.y;
  #pragma unroll
  for (int i = ty; i < 32; i += 8)
    tile[i][tx] = in[(long)(k0 + i) * N + n0 + tx];
  __syncthreads();
  #pragma unroll
  for (int i = ty; i < 32; i += 8)
    out[(long)(n0 + i) * K + k0 + tx] = f2bf(scale * tile[tx][i]);
}

// ---------------- transpose V section of qkv -> vT, k-PERMUTED columns ----------------
// Column position e holds original k = tx with e = 8*((tx>>2)&3) + 4*(tx>>4) + (tx&3),
// matching flash's in-register-P A-fragment k-order (round 6/7, verified).
__global__ void k_transpose_v(const unsigned short* __restrict__ qkv,
                              unsigned short* __restrict__ vT) {
  __shared__ unsigned short tile[32][33];
  int c0 = blockIdx.x * 32;   // within 512 (= g*64+d)
  int l0 = blockIdx.y * 32;
  int b  = blockIdx.z;
  int tx = threadIdx.x, ty = threadIdx.y;
  #pragma unroll
  for (int i = ty; i < 32; i += 8)
    tile[i][tx] = qkv[((long)b * LSEQ + l0 + i) * NQKV + VOFF + c0 + tx];
  __syncthreads();
  int e = 8 * ((tx >> 2) & 3) + 4 * (tx >> 4) + (tx & 3);
  #pragma unroll
  for (int i = ty; i < 32; i += 8)
    vT[((long)b * 512 + c0 + i) * LSEQ + l0 + e] = tile[tx][i];
}

// ---------------- RoPE tables ----------------
__global__ void k_rope_table(float* __restrict__ cosT, float* __restrict__ sinT) {
  int i = blockIdx.x * 256 + threadIdx.x;  // < LSEQ*32
  int t = i >> 5, j = i & 31;
  float inv = powf(10000.0f, -(float)j / 32.0f);
  float fr = (float)t * inv;
  cosT[i] = cosf(fr);
  sinT[i] = sinf(fr);
}

// ---------------- GEMM v5: 128^2 tile, BK=64, swizzled 128B-row LDS ----------------
// Round-10: round-9's 64x128 retile regressed (work-per-drain halved; wrong-axis swizzle
// RAISED conflicts to 9.4M cy) -- reverted to the round-8 m97 128^2 map, changing ONE
// axis: BK 32->64. (a) per-K-step vmcnt-drain/barrier cost amortized over 32 MFMA (was
// 16); (b) LDS rows widen 64B->128B with the flash-PROVEN XOR swizzle (byte ^=
// (row&7)<<4, both-sides: inverse-swizzled global source col, lane-constant (fr&7)<<4
// read XOR since row&7==fr&7) -- kills the BK=32 layout's 8-way ds_read_b128 conflict
// (6.3M cy, ~12% of kernel). LDS stays 32KB (16K A + 16K B, single-buffered) -> same
// 3 blocks/CU (grid-capped). m132's BK=128 failure was the 64KB-LDS occupancy cliff;
// BK=64 avoids it. RoPE epilogue identical to round 8 (verified).
template<bool BF16OUT, bool ROPE>
__global__ __launch_bounds__(256) void k_gemm_bt(
    const unsigned short* __restrict__ A, const unsigned short* __restrict__ Bt,
    void* __restrict__ Cv, int M, int N, int K,
    const float* __restrict__ cosT, const float* __restrict__ sinT) {
  __shared__ __align__(16) char AsB[16384];   // [128 rows][128B], swizzled
  __shared__ __align__(16) char BsB[16384];   // [128 rows][128B], swizzled
  int t = threadIdx.x;
  int lane = t & 63, wave = t >> 6;
  int fr = lane & 15, fg = lane >> 4;
  long rowA = (long)blockIdx.x * 128;
  long rowB = (long)blockIdx.y * 128;
  long K2 = (long)K * 2;

  // staging: thread t covers rows (t>>3)+p*32, 16B granule (t&7) of the 128B row;
  // source col-byte inverse-swizzled so the linear DMA dest lands swizzled (rule #21).
  int scol = ((t & 7) * 16) ^ (((t >> 3) & 7) << 4);
  const char* ApB = (const char*)A  + (rowA + (t >> 3)) * K2 + scol;
  const char* BpB = (const char*)Bt + (rowB + (t >> 3)) * K2 + scol;

  f32x4 acc[4][4] = {};
  int wr = (wave >> 1) * 64, wc = (wave & 1) * 64;
  int sw8 = (fr & 7) << 4;   // read-side XOR: row&7 == fr&7 (wr, i*16 are mult of 8? 16 yes)

  for (int kt = 0; kt < K; kt += 64) {
    #pragma unroll
    for (int p = 0; p < 4; p++) {
      gload_lds16(ApB + (long)(p * 32) * K2 + kt * 2, AsB + p * 4096 + t * 16);
      gload_lds16(BpB + (long)(p * 32) * K2 + kt * 2, BsB + p * 4096 + t * 16);
    }
    __syncthreads();
    #pragma unroll
    for (int ks = 0; ks < 2; ks++) {
      bf16x8 af[4], bfv[4];
      #pragma unroll
      for (int i = 0; i < 4; i++)
        af[i] = *(const bf16x8*)(AsB + (wr + i * 16 + fr) * 128 + ((ks * 64 + fg * 16) ^ sw8));
      #pragma unroll
      for (int j = 0; j < 4; j++)
        bfv[j] = *(const bf16x8*)(BsB + (wc + j * 16 + fr) * 128 + ((ks * 64 + fg * 16) ^ sw8));
      #pragma unroll
      for (int i = 0; i < 4; i++) {
        #pragma unroll
        for (int j = 0; j < 4; j++)
          acc[i][j] = __builtin_amdgcn_mfma_f32_16x16x32_bf16(af[i], bfv[j], acc[i][j], 0, 0, 0);
      }
    }
    __syncthreads();
  }

  long colbase = rowB + wc;
  bool rope_sec = ROPE && (colbase < VOFF);   // Q or K head (col < 2560); wave-uniform
  #pragma unroll
  for (int i = 0; i < 4; i++) {
    #pragma unroll
    for (int r = 0; r < 4; r++) {
      long row = rowA + wr + i * 16 + fg * 4 + r;
      if (ROPE && rope_sec) {
        int tpos = (int)(row & (LSEQ - 1));
        #pragma unroll
        for (int j = 0; j < 2; j++) {   // pair (d = j*16+fr, d+32 = (j+2)*16+fr)
          int jj = j * 16 + fr;
          float c = cosT[tpos * 32 + jj];
          float s = sinT[tpos * 32 + jj];
          float lo = acc[i][j][r], hi = acc[i][j + 2][r];
          ((unsigned short*)Cv)[row * N + colbase + j * 16 + fr]       = f2bf(lo * c - hi * s);
          ((unsigned short*)Cv)[row * N + colbase + (j + 2) * 16 + fr] = f2bf(hi * c + lo * s);
        }
      } else {
        #pragma unroll
        for (int j = 0; j < 4; j++) {
          long col = colbase + j * 16 + fr;
          if (BF16OUT) ((unsigned short*)Cv)[row * N + col] = f2bf(acc[i][j][r]);
          else         ((float*)Cv)[row * N + col] = acc[i][j][r];
        }
      }
    }
  }
}

// ---------------- flash attention v16: in-register P (round-7, verified) ----------------
// Swapped QK (mfma(K,Q)) -> P lane-local per q-column; register-only bf16 pack
// (static-index vector inserts -- the round-6 union idiom went to scratch, rule #20);
// V k-order permuted in k_transpose_v to match A-frag slot order; static-max softmax
// (wq pre-scaled into exp2 domain); LDS 48KB -> 3 blocks/CU.
__global__ __launch_bounds__(256, 3) void k_flash_attn13(
    const unsigned short* __restrict__ qkv, const unsigned short* __restrict__ vT,
    unsigned short* __restrict__ attn) {
  int g0 = (int)blockIdx.x;
  int hb = g0 & 63;
  int h = hb & 31, b = hb >> 5;
  int qt = 15 - (g0 >> 6);            // heavy blocks first (backfill smooths the tail)
  int g = h >> 2;
  int t = threadIdx.x, lane = t & 63, wave = t >> 6;
  int fr = lane & 15, fg = lane >> 4;

  __shared__ __align__(16) char KT[16384];              // 16KB: K tile [128 rows][128B], swz
  __shared__ __align__(16) char VT2[2][16384];          // 32KB: V tile [64 rows][256B], swz, dbuf
  long rowbase = (long)b * LSEQ;

  int qbaseA = qt * 128 + wave * 32;
  int qbaseB = qbaseA + 16;

  const unsigned short* qpA = &qkv[(rowbase + qbaseA + fr) * NQKV + h * 64 + fg * 8];
  const unsigned short* qpB = &qkv[(rowbase + qbaseB + fr) * NQKV + h * 64 + fg * 8];
  bf16x8 qfA0 = *(const bf16x8*)(qpA);
  bf16x8 qfA1 = *(const bf16x8*)(qpA + 32);
  bf16x8 qfB0 = *(const bf16x8*)(qpB);
  bf16x8 qfB1 = *(const bf16x8*)(qpB + 32);

  int kcb = ((t & 7) * 16) ^ (((t >> 3) & 7) << 4);    // K: 128B rows, row = p*32 + (t>>3)
  int vcb = ((t & 15) * 16) ^ (((t >> 4) & 7) << 4);   // V: 256B rows, row = p*16 + (t>>4)

  const char* kgb = (const char*)qkv;
  const char* vgb = (const char*)vT;
  long ksrc0 = ((rowbase) * (long)NQKV + KOFF + (long)g * 64) * 2;
  long vsrc0 = (((long)(b * 512 + g * 64)) * LSEQ) * 2;

  auto stageK = [&](int kbase) {
    #pragma unroll
    for (int p = 0; p < 4; p++) {
      int krow = p * 32 + (t >> 3);
      gload_lds16(kgb + ksrc0 + (long)(kbase + krow) * (NQKV * 2) + kcb,
                  KT + p * 4096 + t * 16);
    }
  };
  auto stageV = [&](int kbase, char* dst) {
    #pragma unroll
    for (int p = 0; p < 4; p++) {
      int vrow = p * 16 + (t >> 4);
      gload_lds16(vgb + vsrc0 + (long)vrow * (LSEQ * 2) + kbase * 2 + vcb,
                  dst + p * 4096 + t * 16);
    }
  };

  stageK(0);
  stageV(0, VT2[0]);

  f32x4 poA[4] = {}, poB[4] = {};
  float lA = 0.f, lB = 0.f;   // per-lane partial denominators for q = qbase+fr

  int sw8 = (fr & 7) << 4;

  for (int kt = 0; kt <= qt; kt++) {
    int kbase = kt * 128;
    __syncthreads();   // B1: staged K/V landed; all waves' prev-iter LDS reads done

    // V restage WAR-safe at B1 (prev PV readers of this buffer synced); full-iter cover
    if (kt < qt) stageV(kbase + 128, VT2[(kt + 1) & 1]);

    f32x4 stA[8], stB[8];
    __builtin_amdgcn_s_setprio(1);
    #pragma unroll
    for (int s = 0; s < 8; s++) {
      const char* kr = KT + ((s * 16 + fr) << 7);
      bf16x8 kf0 = *(const bf16x8*)(kr + ((fg * 16) ^ sw8));
      bf16x8 kf1 = *(const bf16x8*)(kr + ((fg * 16 + 64) ^ sw8));
      f32x4 a = {};
      a = __builtin_amdgcn_mfma_f32_16x16x32_bf16(kf0, qfA0, a, 0, 0, 0);
      a = __builtin_amdgcn_mfma_f32_16x16x32_bf16(kf1, qfA1, a, 0, 0, 0);
      stA[s] = a;
      f32x4 c = {};
      c = __builtin_amdgcn_mfma_f32_16x16x32_bf16(kf0, qfB0, c, 0, 0, 0);
      c = __builtin_amdgcn_mfma_f32_16x16x32_bf16(kf1, qfB1, c, 0, 0, 0);
      stB[s] = c;
    }
    __builtin_amdgcn_s_setprio(0);
    __syncthreads();   // B2: all waves' K ds_reads retired -> K restage safe

    if (kt < qt) stageK(kbase + 128);   // lands by next B1; softmax+PV cover

    if (kt == qt) {   // diagonal tile: causal mask (k = kbase+s*16+fg*4+r, q = qbase+fr)
      #pragma unroll
      for (int s = 0; s < 8; s++) {
        #pragma unroll
        for (int r = 0; r < 4; r++) {
          int kp = kbase + s * 16 + fg * 4 + r;
          if (kp > qbaseA + fr) stA[s][r] = -1e30f;
          if (kp > qbaseB + fr) stB[s][r] = -1e30f;
        }
      }
    }

    // softmax (static-max, pre-scaled exp2 domain) + register-only bf16 pack.
    // A-frag slot (fg, j): j=r -> k32 = 4*fg + r ; j=4+r -> k32 = 16 + 4*fg + r.
    bf16x8 paA[4], paB[4];
    #pragma unroll
    for (int km = 0; km < 4; km++) {
      bf16x8 pa, pb;
      #pragma unroll
      for (int r = 0; r < 4; r++) {
        float peA = exp2f(stA[2 * km][r]);
        float pqA = exp2f(stA[2 * km + 1][r]);
        lA += peA + pqA;
        pa[r]     = (__bf16)peA;
        pa[r + 4] = (__bf16)pqA;
        float peB = exp2f(stB[2 * km][r]);
        float pqB = exp2f(stB[2 * km + 1][r]);
        lB += peB + pqB;
        pb[r]     = (__bf16)peB;
        pb[r + 4] = (__bf16)pqB;
      }
      paA[km] = pa;
      paB[km] = pb;
    }

    const char* Vb = VT2[kt & 1];
    __builtin_amdgcn_s_setprio(1);
    #pragma unroll
    for (int km = 0; km < 4; km++) {
      #pragma unroll
      for (int dt = 0; dt < 4; dt++) {
        const char* vr = Vb + ((dt * 16 + fr) << 8);
        bf16x8 vf = *(const bf16x8*)(vr + ((km * 64 + fg * 16) ^ sw8));
        poA[dt] = __builtin_amdgcn_mfma_f32_16x16x32_bf16(paA[km], vf, poA[dt], 0, 0, 0);
        poB[dt] = __builtin_amdgcn_mfma_f32_16x16x32_bf16(paB[km], vf, poB[dt], 0, 0, 0);
      }
    }
    __builtin_amdgcn_s_setprio(0);
    // no trailing barrier: next B1 orders LDS reads vs. restaging
  }

  // denominator: reduce per-lane partials over the fg-group (lanes fr, fr+16, fr+32, fr+48)
  lA += __shfl_xor(lA, 16, 64); lA += __shfl_xor(lA, 32, 64);
  lB += __shfl_xor(lB, 16, 64); lB += __shfl_xor(lB, 32, 64);

  // po[dt][r] is O[q = qbase + fg*4 + r][d = dt*16 + fr]; l for q-local i lives on lanes
  // with fr == i -> fetch via shfl from lane fg*4+r (fg=0 copy).
  #pragma unroll
  for (int r = 0; r < 4; r++) {
    float liA = 1.0f / __shfl(lA, fg * 4 + r, 64);
    float liB = 1.0f / __shfl(lB, fg * 4 + r, 64);
    #pragma unroll
    for (int dt = 0; dt < 4; dt++) {
      attn[(rowbase + qbaseA + fg * 4 + r) * DIM + h * 64 + dt * 16 + fr] = f2bf(poA[dt][r] * liA);
      attn[(rowbase + qbaseB + fg * 4 + r) * DIM + h * 64 + dt * 16 + fr] = f2bf(poB[dt][r] * liB);
    }
  }
}

extern "C" void kernel_launch(void* const* d_in, const int* in_sizes, int n_in,
                              void* d_out, int out_size, void* d_ws, size_t ws_size,
                              hipStream_t stream) {
  const float* x  = (const float*)d_in[0];
  const float* wq = (const float*)d_in[1];
  const float* wk = (const float*)d_in[2];
  const float* wv = (const float*)d_in[3];
  const float* wo = (const float*)d_in[4];

  char* ws = (char*)d_ws;
  unsigned short* xb    = (unsigned short*)(ws);                 // 16.78 MB (reused as vT later)
  unsigned short* wqkvT = (unsigned short*)(ws + 16777216);      // 12.58 MB [3072][2048]
  unsigned short* woT   = (unsigned short*)(ws + 29360128);      //  8.39 MB [2048][2048]
  unsigned short* qkv   = (unsigned short*)(ws + 37748736);      // 25.17 MB [4096][3072]
  unsigned short* attn  = (unsigned short*)(ws + 62914560);      // 16.78 MB [4096][2048]
  float* cosT           = (float*)(ws + 79691776);               // 256 KB
  float* sinT           = (float*)(ws + 79953920);               // 256 KB
  unsigned short* vT    = xb;                                    // alias: xb dead after QKV GEMM

  const float C2 = 0.125f * 1.44269504f;   // 1/sqrt(64) * log2(e), folded into wq

  k_cvt_x<<<8192, 256, 0, stream>>>(x, xb, M_ROWS * DIM / 4);
  dim3 tb(32, 8);
  k_transpose_bf16<<<dim3(DIM/32, DIM/32), tb, 0, stream>>>(wq, wqkvT, DIM, DIM, C2);
  k_transpose_bf16<<<dim3(512/32, DIM/32), tb, 0, stream>>>(wk, wqkvT + (long)2048*2048, DIM, 512, 1.0f);
  k_transpose_bf16<<<dim3(512/32, DIM/32), tb, 0, stream>>>(wv, wqkvT + (long)2560*2048, DIM, 512, 1.0f);
  k_transpose_bf16<<<dim3(DIM/32, DIM/32), tb, 0, stream>>>(wo, woT, DIM, DIM, 1.0f);
  k_rope_table<<<(LSEQ*32)/256, 256, 0, stream>>>(cosT, sinT);

  // 128^2-tile BK=64 GEMMs; QKV fuses the RoPE epilogue (k_rope_apply deleted, round 8)
  k_gemm_bt<true, true><<<dim3(M_ROWS/128, NQKV/128), 256, 0, stream>>>(
      xb, wqkvT, qkv, M_ROWS, NQKV, DIM, cosT, sinT);
  k_transpose_v<<<dim3(16, 64, 2), tb, 0, stream>>>(qkv, vT);
  k_flash_attn13<<<1024, 256, 0, stream>>>(qkv, vT, attn);
  k_gemm_bt<false, false><<<dim3(M_ROWS/128, DIM/128), 256, 0, stream>>>(
      attn, woT, d_out, M_ROWS, DIM, DIM, nullptr, nullptr);
}

// Round 11
// 190.153 us; speedup vs baseline: 1.3106x; 1.0272x over previous
//
#include <hip/hip_runtime.h>
#include <stdint.h>

#define DIM   2048
#define LSEQ  2048
#define BATCH 2
#define NH    32
#define NKV   8
#define HD    64
#define M_ROWS (BATCH*LSEQ)       // 4096
#define NQKV  (DIM + 2*NKV*HD)    // 3072
#define KOFF  DIM                 // 2048
#define VOFF  (DIM + NKV*HD)      // 2560

typedef __attribute__((ext_vector_type(8))) __bf16 bf16x8;
typedef __attribute__((ext_vector_type(8))) unsigned short u16x8;
typedef __attribute__((ext_vector_type(4))) float f32x4;

// hardware RNE f32->bf16 (harness-verified rounds 2-10)
__device__ __forceinline__ unsigned short f2bf(float f) {
  union { __bf16 h; unsigned short u; } v;
  v.h = (__bf16)f;
  return v.u;
}
__device__ __forceinline__ float bf2f(unsigned short h) {
  union { unsigned u; float f; } v; v.u = ((unsigned)h) << 16;
  return v.f;
}

__device__ __forceinline__ void gload_lds16(const void* g, void* l) {
  __builtin_amdgcn_global_load_lds(
      (__attribute__((address_space(1))) unsigned int*)g,
      (__attribute__((address_space(3))) unsigned int*)l, 16, 0, 0);
}

// ---------------- fp32 -> bf16 convert (vectorized) ----------------
__global__ void k_cvt_x(const float* __restrict__ in, unsigned short* __restrict__ out, int n4) {
  int i = blockIdx.x * blockDim.x + threadIdx.x;
  if (i >= n4) return;
  float4 v = ((const float4*)in)[i];
  ushort4 o;
  o.x = f2bf(v.x); o.y = f2bf(v.y); o.z = f2bf(v.z); o.w = f2bf(v.w);
  ((ushort4*)out)[i] = o;
}

// ---------------- transpose + cast + scale: out[n][k] = bf16(scale*in[k][n]) ----------------
// scale folds softmax 1/sqrt(d)*log2(e) into wq (commutes with RoPE rotation + GEMM).
__global__ void k_transpose_bf16(const float* __restrict__ in, unsigned short* __restrict__ out,
                                 int K, int N, float scale) {
  __shared__ float tile[32][33];
  int n0 = blockIdx.x * 32, k0 = blockIdx.y * 32;
  int tx = threadIdx.x, ty = threadIdx.y;
  #pragma unroll
  for (int i = ty; i < 32; i += 8)
    tile[i][tx] = in[(long)(k0 + i) * N + n0 + tx];
  __syncthreads();
  #pragma unroll
  for (int i = ty; i < 32; i += 8)
    out[(long)(n0 + i) * K + k0 + tx] = f2bf(scale * tile[tx][i]);
}

// ---------------- transpose V section of qkv -> vT, k-PERMUTED columns ----------------
// Column position e holds original k = tx with e = 8*((tx>>2)&3) + 4*(tx>>4) + (tx&3),
// matching flash's in-register-P A-fragment k-order (round 6/7, verified).
__global__ void k_transpose_v(const unsigned short* __restrict__ qkv,
                              unsigned short* __restrict__ vT) {
  __shared__ unsigned short tile[32][33];
  int c0 = blockIdx.x * 32;   // within 512 (= g*64+d)
  int l0 = blockIdx.y * 32;
  int b  = blockIdx.z;
  int tx = threadIdx.x, ty = threadIdx.y;
  #pragma unroll
  for (int i = ty; i < 32; i += 8)
    tile[i][tx] = qkv[((long)b * LSEQ + l0 + i) * NQKV + VOFF + c0 + tx];
  __syncthreads();
  int e = 8 * ((tx >> 2) & 3) + 4 * (tx >> 4) + (tx & 3);
  #pragma unroll
  for (int i = ty; i < 32; i += 8)
    vT[((long)b * 512 + c0 + i) * LSEQ + l0 + e] = tile[tx][i];
}

// ---------------- RoPE tables ----------------
__global__ void k_rope_table(float* __restrict__ cosT, float* __restrict__ sinT) {
  int i = blockIdx.x * 256 + threadIdx.x;  // < LSEQ*32
  int t = i >> 5, j = i & 31;
  float inv = powf(10000.0f, -(float)j / 32.0f);
  float fr = (float)t * inv;
  cosT[i] = cosf(fr);
  sinT[i] = sinf(fr);
}

// ---------------- GEMM v5: 128^2 tile, BK=64, swizzled 128B-row LDS (round-10, verified) ----------------
// QKV path: single-buffered 32KB LDS -> 3 blocks/CU (grid 768 = 3/CU). Conflict-free
// (0 measured r10). RoPE epilogue fused (verified round 8).
template<bool BF16OUT, bool ROPE>
__global__ __launch_bounds__(256) void k_gemm_bt(
    const unsigned short* __restrict__ A, const unsigned short* __restrict__ Bt,
    void* __restrict__ Cv, int M, int N, int K,
    const float* __restrict__ cosT, const float* __restrict__ sinT) {
  __shared__ __align__(16) char AsB[16384];   // [128 rows][128B], swizzled
  __shared__ __align__(16) char BsB[16384];   // [128 rows][128B], swizzled
  int t = threadIdx.x;
  int lane = t & 63, wave = t >> 6;
  int fr = lane & 15, fg = lane >> 4;
  long rowA = (long)blockIdx.x * 128;
  long rowB = (long)blockIdx.y * 128;
  long K2 = (long)K * 2;

  int scol = ((t & 7) * 16) ^ (((t >> 3) & 7) << 4);
  const char* ApB = (const char*)A  + (rowA + (t >> 3)) * K2 + scol;
  const char* BpB = (const char*)Bt + (rowB + (t >> 3)) * K2 + scol;

  f32x4 acc[4][4] = {};
  int wr = (wave >> 1) * 64, wc = (wave & 1) * 64;
  int sw8 = (fr & 7) << 4;

  for (int kt = 0; kt < K; kt += 64) {
    #pragma unroll
    for (int p = 0; p < 4; p++) {
      gload_lds16(ApB + (long)(p * 32) * K2 + kt * 2, AsB + p * 4096 + t * 16);
      gload_lds16(BpB + (long)(p * 32) * K2 + kt * 2, BsB + p * 4096 + t * 16);
    }
    __syncthreads();
    #pragma unroll
    for (int ks = 0; ks < 2; ks++) {
      bf16x8 af[4], bfv[4];
      #pragma unroll
      for (int i = 0; i < 4; i++)
        af[i] = *(const bf16x8*)(AsB + (wr + i * 16 + fr) * 128 + ((ks * 64 + fg * 16) ^ sw8));
      #pragma unroll
      for (int j = 0; j < 4; j++)
        bfv[j] = *(const bf16x8*)(BsB + (wc + j * 16 + fr) * 128 + ((ks * 64 + fg * 16) ^ sw8));
      #pragma unroll
      for (int i = 0; i < 4; i++) {
        #pragma unroll
        for (int j = 0; j < 4; j++)
          acc[i][j] = __builtin_amdgcn_mfma_f32_16x16x32_bf16(af[i], bfv[j], acc[i][j], 0, 0, 0);
      }
    }
    __syncthreads();
  }

  long colbase = rowB + wc;
  bool rope_sec = ROPE && (colbase < VOFF);   // Q or K head (col < 2560); wave-uniform
  #pragma unroll
  for (int i = 0; i < 4; i++) {
    #pragma unroll
    for (int r = 0; r < 4; r++) {
      long row = rowA + wr + i * 16 + fg * 4 + r;
      if (ROPE && rope_sec) {
        int tpos = (int)(row & (LSEQ - 1));
        #pragma unroll
        for (int j = 0; j < 2; j++) {   // pair (d = j*16+fr, d+32 = (j+2)*16+fr)
          int jj = j * 16 + fr;
          float c = cosT[tpos * 32 + jj];
          float s = sinT[tpos * 32 + jj];
          float lo = acc[i][j][r], hi = acc[i][j + 2][r];
          ((unsigned short*)Cv)[row * N + colbase + j * 16 + fr]       = f2bf(lo * c - hi * s);
          ((unsigned short*)Cv)[row * N + colbase + (j + 2) * 16 + fr] = f2bf(hi * c + lo * s);
        }
      } else {
        #pragma unroll
        for (int j = 0; j < 4; j++) {
          long col = colbase + j * 16 + fr;
          if (BF16OUT) ((unsigned short*)Cv)[row * N + col] = f2bf(acc[i][j][r]);
          else         ((float*)Cv)[row * N + col] = acc[i][j][r];
        }
      }
    }
  }
}

// ---------------- GEMM v6 (WO): double-buffered BK=64, single-barrier pipeline ----------------
// Round-11: WO grid = 512 blocks = 2/CU exactly (grid-capped below QKV's 3/CU) -> 80KB
// LDS headroom per block is FREE. Double-buffer both tiles (64KB) and restructure to ONE
// barrier per K-tile: top-of-iter {vmcnt(0): waits tile-kt loads issued a FULL ITERATION
// ago (real cover: 8 ds_read + 32 MFMA ~300cy vs ~200cy L2 latency) -> s_barrier ->
// sched_barrier(0)} -> ds_read ks=0 frags -> ISSUE stage(kt+1 -> other buf) -> MFMA.
// WAR audit: stage targets the buffer last read in iter kt-1; every wave past the
// top-of-kt barrier consumed (lgkm-waited) those reads inside iter kt-1 -> all readers
// retired. vmcnt audit: exactly 8 loads in flight per wave at each wait; prologue
// stages tile 0 then drains. Replaces m97's 2-barrier + exposed-drain structure for WO.
__global__ __launch_bounds__(256) void k_gemm_db(
    const unsigned short* __restrict__ A, const unsigned short* __restrict__ Bt,
    float* __restrict__ Cv, int M, int N, int K) {
  __shared__ __align__(16) char AsB[2][16384];   // [buf][128 rows][128B], swizzled
  __shared__ __align__(16) char BsB[2][16384];
  int t = threadIdx.x;
  int lane = t & 63, wave = t >> 6;
  int fr = lane & 15, fg = lane >> 4;
  long rowA = (long)blockIdx.x * 128;
  long rowB = (long)blockIdx.y * 128;
  long K2 = (long)K * 2;

  int scol = ((t & 7) * 16) ^ (((t >> 3) & 7) << 4);
  const char* ApB = (const char*)A  + (rowA + (t >> 3)) * K2 + scol;
  const char* BpB = (const char*)Bt + (rowB + (t >> 3)) * K2 + scol;

  auto stage = [&](int kt, int bi) {   // kt in 64-elem tiles; 8 loads/thread
    #pragma unroll
    for (int p = 0; p < 4; p++) {
      gload_lds16(ApB + (long)(p * 32) * K2 + (long)kt * 128, AsB[bi] + p * 4096 + t * 16);
      gload_lds16(BpB + (long)(p * 32) * K2 + (long)kt * 128, BsB[bi] + p * 4096 + t * 16);
    }
  };

  f32x4 acc[4][4] = {};
  int wr = (wave >> 1) * 64, wc = (wave & 1) * 64;
  int sw8 = (fr & 7) << 4;
  int NT = K >> 6;

  stage(0, 0);
  for (int kt = 0; kt < NT; kt++) {
    int cur = kt & 1;
    // tile kt's 8 loads are the only outstanding VMEM; issued a full iteration ago
    asm volatile("s_waitcnt vmcnt(0)" ::: "memory");
    __builtin_amdgcn_s_barrier();
    __builtin_amdgcn_sched_barrier(0);
    const char* Ac = AsB[cur];
    const char* Bc = BsB[cur];
    #pragma unroll
    for (int ks = 0; ks < 2; ks++) {
      bf16x8 af[4], bfv[4];
      #pragma unroll
      for (int i = 0; i < 4; i++)
        af[i] = *(const bf16x8*)(Ac + (wr + i * 16 + fr) * 128 + ((ks * 64 + fg * 16) ^ sw8));
      #pragma unroll
      for (int j = 0; j < 4; j++)
        bfv[j] = *(const bf16x8*)(Bc + (wc + j * 16 + fr) * 128 + ((ks * 64 + fg * 16) ^ sw8));
      if (ks == 0 && kt + 1 < NT) stage(kt + 1, cur ^ 1);   // issue under reads+MFMA
      #pragma unroll
      for (int i = 0; i < 4; i++) {
        #pragma unroll
        for (int j = 0; j < 4; j++)
          acc[i][j] = __builtin_amdgcn_mfma_f32_16x16x32_bf16(af[i], bfv[j], acc[i][j], 0, 0, 0);
      }
    }
    // no trailing barrier: next iter's top barrier orders reads vs. restage
  }

  #pragma unroll
  for (int i = 0; i < 4; i++) {
    #pragma unroll
    for (int j = 0; j < 4; j++) {
      #pragma unroll
      for (int r = 0; r < 4; r++) {
        long row = rowA + wr + i * 16 + fg * 4 + r;
        long col = rowB + wc + j * 16 + fr;
        Cv[row * N + col] = acc[i][j][r];
      }
    }
  }
}

// ---------------- flash attention v16: in-register P (round-7, verified) ----------------
// Swapped QK (mfma(K,Q)) -> P lane-local per q-column; register-only bf16 pack
// (static-index vector inserts -- the round-6 union idiom went to scratch, rule #20);
// V k-order permuted in k_transpose_v to match A-frag slot order; static-max softmax
// (wq pre-scaled into exp2 domain); LDS 48KB -> 3 blocks/CU.
__global__ __launch_bounds__(256, 3) void k_flash_attn13(
    const unsigned short* __restrict__ qkv, const unsigned short* __restrict__ vT,
    unsigned short* __restrict__ attn) {
  int g0 = (int)blockIdx.x;
  int hb = g0 & 63;
  int h = hb & 31, b = hb >> 5;
  int qt = 15 - (g0 >> 6);            // heavy blocks first (backfill smooths the tail)
  int g = h >> 2;
  int t = threadIdx.x, lane = t & 63, wave = t >> 6;
  int fr = lane & 15, fg = lane >> 4;

  __shared__ __align__(16) char KT[16384];              // 16KB: K tile [128 rows][128B], swz
  __shared__ __align__(16) char VT2[2][16384];          // 32KB: V tile [64 rows][256B], swz, dbuf
  long rowbase = (long)b * LSEQ;

  int qbaseA = qt * 128 + wave * 32;
  int qbaseB = qbaseA + 16;

  const unsigned short* qpA = &qkv[(rowbase + qbaseA + fr) * NQKV + h * 64 + fg * 8];
  const unsigned short* qpB = &qkv[(rowbase + qbaseB + fr) * NQKV + h * 64 + fg * 8];
  bf16x8 qfA0 = *(const bf16x8*)(qpA);
  bf16x8 qfA1 = *(const bf16x8*)(qpA + 32);
  bf16x8 qfB0 = *(const bf16x8*)(qpB);
  bf16x8 qfB1 = *(const bf16x8*)(qpB + 32);

  int kcb = ((t & 7) * 16) ^ (((t >> 3) & 7) << 4);    // K: 128B rows, row = p*32 + (t>>3)
  int vcb = ((t & 15) * 16) ^ (((t >> 4) & 7) << 4);   // V: 256B rows, row = p*16 + (t>>4)

  const char* kgb = (const char*)qkv;
  const char* vgb = (const char*)vT;
  long ksrc0 = ((rowbase) * (long)NQKV + KOFF + (long)g * 64) * 2;
  long vsrc0 = (((long)(b * 512 + g * 64)) * LSEQ) * 2;

  auto stageK = [&](int kbase) {
    #pragma unroll
    for (int p = 0; p < 4; p++) {
      int krow = p * 32 + (t >> 3);
      gload_lds16(kgb + ksrc0 + (long)(kbase + krow) * (NQKV * 2) + kcb,
                  KT + p * 4096 + t * 16);
    }
  };
  auto stageV = [&](int kbase, char* dst) {
    #pragma unroll
    for (int p = 0; p < 4; p++) {
      int vrow = p * 16 + (t >> 4);
      gload_lds16(vgb + vsrc0 + (long)vrow * (LSEQ * 2) + kbase * 2 + vcb,
                  dst + p * 4096 + t * 16);
    }
  };

  stageK(0);
  stageV(0, VT2[0]);

  f32x4 poA[4] = {}, poB[4] = {};
  float lA = 0.f, lB = 0.f;   // per-lane partial denominators for q = qbase+fr

  int sw8 = (fr & 7) << 4;

  for (int kt = 0; kt <= qt; kt++) {
    int kbase = kt * 128;
    __syncthreads();   // B1: staged K/V landed; all waves' prev-iter LDS reads done

    // V restage WAR-safe at B1 (prev PV readers of this buffer synced); full-iter cover
    if (kt < qt) stageV(kbase + 128, VT2[(kt + 1) & 1]);

    f32x4 stA[8], stB[8];
    __builtin_amdgcn_s_setprio(1);
    #pragma unroll
    for (int s = 0; s < 8; s++) {
      const char* kr = KT + ((s * 16 + fr) << 7);
      bf16x8 kf0 = *(const bf16x8*)(kr + ((fg * 16) ^ sw8));
      bf16x8 kf1 = *(const bf16x8*)(kr + ((fg * 16 + 64) ^ sw8));
      f32x4 a = {};
      a = __builtin_amdgcn_mfma_f32_16x16x32_bf16(kf0, qfA0, a, 0, 0, 0);
      a = __builtin_amdgcn_mfma_f32_16x16x32_bf16(kf1, qfA1, a, 0, 0, 0);
      stA[s] = a;
      f32x4 c = {};
      c = __builtin_amdgcn_mfma_f32_16x16x32_bf16(kf0, qfB0, c, 0, 0, 0);
      c = __builtin_amdgcn_mfma_f32_16x16x32_bf16(kf1, qfB1, c, 0, 0, 0);
      stB[s] = c;
    }
    __builtin_amdgcn_s_setprio(0);
    __syncthreads();   // B2: all waves' K ds_reads retired -> K restage safe

    if (kt < qt) stageK(kbase + 128);   // lands by next B1; softmax+PV cover

    if (kt == qt) {   // diagonal tile: causal mask (k = kbase+s*16+fg*4+r, q = qbase+fr)
      #pragma unroll
      for (int s = 0; s < 8; s++) {
        #pragma unroll
        for (int r = 0; r < 4; r++) {
          int kp = kbase + s * 16 + fg * 4 + r;
          if (kp > qbaseA + fr) stA[s][r] = -1e30f;
          if (kp > qbaseB + fr) stB[s][r] = -1e30f;
        }
      }
    }

    // softmax (static-max, pre-scaled exp2 domain) + register-only bf16 pack.
    // A-frag slot (fg, j): j=r -> k32 = 4*fg + r ; j=4+r -> k32 = 16 + 4*fg + r.
    bf16x8 paA[4], paB[4];
    #pragma unroll
    for (int km = 0; km < 4; km++) {
      bf16x8 pa, pb;
      #pragma unroll
      for (int r = 0; r < 4; r++) {
        float peA = exp2f(stA[2 * km][r]);
        float pqA = exp2f(stA[2 * km + 1][r]);
        lA += peA + pqA;
        pa[r]     = (__bf16)peA;
        pa[r + 4] = (__bf16)pqA;
        float peB = exp2f(stB[2 * km][r]);
        float pqB = exp2f(stB[2 * km + 1][r]);
        lB += peB + pqB;
        pb[r]     = (__bf16)peB;
        pb[r + 4] = (__bf16)pqB;
      }
      paA[km] = pa;
      paB[km] = pb;
    }

    const char* Vb = VT2[kt & 1];
    __builtin_amdgcn_s_setprio(1);
    #pragma unroll
    for (int km = 0; km < 4; km++) {
      #pragma unroll
      for (int dt = 0; dt < 4; dt++) {
        const char* vr = Vb + ((dt * 16 + fr) << 8);
        bf16x8 vf = *(const bf16x8*)(vr + ((km * 64 + fg * 16) ^ sw8));
        poA[dt] = __builtin_amdgcn_mfma_f32_16x16x32_bf16(paA[km], vf, poA[dt], 0, 0, 0);
        poB[dt] = __builtin_amdgcn_mfma_f32_16x16x32_bf16(paB[km], vf, poB[dt], 0, 0, 0);
      }
    }
    __builtin_amdgcn_s_setprio(0);
    // no trailing barrier: next B1 orders LDS reads vs. restaging
  }

  // denominator: reduce per-lane partials over the fg-group (lanes fr, fr+16, fr+32, fr+48)
  lA += __shfl_xor(lA, 16, 64); lA += __shfl_xor(lA, 32, 64);
  lB += __shfl_xor(lB, 16, 64); lB += __shfl_xor(lB, 32, 64);

  // po[dt][r] is O[q = qbase + fg*4 + r][d = dt*16 + fr]; l for q-local i lives on lanes
  // with fr == i -> fetch via shfl from lane fg*4+r (fg=0 copy).
  #pragma unroll
  for (int r = 0; r < 4; r++) {
    float liA = 1.0f / __shfl(lA, fg * 4 + r, 64);
    float liB = 1.0f / __shfl(lB, fg * 4 + r, 64);
    #pragma unroll
    for (int dt = 0; dt < 4; dt++) {
      attn[(rowbase + qbaseA + fg * 4 + r) * DIM + h * 64 + dt * 16 + fr] = f2bf(poA[dt][r] * liA);
      attn[(rowbase + qbaseB + fg * 4 + r) * DIM + h * 64 + dt * 16 + fr] = f2bf(poB[dt][r] * liB);
    }
  }
}

extern "C" void kernel_launch(void* const* d_in, const int* in_sizes, int n_in,
                              void* d_out, int out_size, void* d_ws, size_t ws_size,
                              hipStream_t stream) {
  const float* x  = (const float*)d_in[0];
  const float* wq = (const float*)d_in[1];
  const float* wk = (const float*)d_in[2];
  const float* wv = (const float*)d_in[3];
  const float* wo = (const float*)d_in[4];

  char* ws = (char*)d_ws;
  unsigned short* xb    = (unsigned short*)(ws);                 // 16.78 MB (reused as vT later)
  unsigned short* wqkvT = (unsigned short*)(ws + 16777216);      // 12.58 MB [3072][2048]
  unsigned short* woT   = (unsigned short*)(ws + 29360128);      //  8.39 MB [2048][2048]
  unsigned short* qkv   = (unsigned short*)(ws + 37748736);      // 25.17 MB [4096][3072]
  unsigned short* attn  = (unsigned short*)(ws + 62914560);      // 16.78 MB [4096][2048]
  float* cosT           = (float*)(ws + 79691776);               // 256 KB
  float* sinT           = (float*)(ws + 79953920);               // 256 KB
  unsigned short* vT    = xb;                                    // alias: xb dead after QKV GEMM

  const float C2 = 0.125f * 1.44269504f;   // 1/sqrt(64) * log2(e), folded into wq

  k_cvt_x<<<8192, 256, 0, stream>>>(x, xb, M_ROWS * DIM / 4);
  dim3 tb(32, 8);
  k_transpose_bf16<<<dim3(DIM/32, DIM/32), tb, 0, stream>>>(wq, wqkvT, DIM, DIM, C2);
  k_transpose_bf16<<<dim3(512/32, DIM/32), tb, 0, stream>>>(wk, wqkvT + (long)2048*2048, DIM, 512, 1.0f);
  k_transpose_bf16<<<dim3(512/32, DIM/32), tb, 0, stream>>>(wv, wqkvT + (long)2560*2048, DIM, 512, 1.0f);
  k_transpose_bf16<<<dim3(DIM/32, DIM/32), tb, 0, stream>>>(wo, woT, DIM, DIM, 1.0f);
  k_rope_table<<<(LSEQ*32)/256, 256, 0, stream>>>(cosT, sinT);

  // QKV: round-10 single-buffered BK=64 (3 blocks/CU, verified 68us) + fused RoPE
  k_gemm_bt<true, true><<<dim3(M_ROWS/128, NQKV/128), 256, 0, stream>>>(
      xb, wqkvT, qkv, M_ROWS, NQKV, DIM, cosT, sinT);
  k_transpose_v<<<dim3(16, 64, 2), tb, 0, stream>>>(qkv, vT);
  k_flash_attn13<<<1024, 256, 0, stream>>>(qkv, vT, attn);
  // WO: double-buffered single-barrier pipeline (2 blocks/CU grid-capped -> dbuf is free)
  k_gemm_db<<<dim3(M_ROWS/128, DIM/128), 256, 0, stream>>>(
      attn, woT, (float*)d_out, M_ROWS, DIM, DIM);
}